// Round 14
// baseline (106.824 us; speedup 1.0000x reference)
//
#include <hip/hip_runtime.h>

#define BB 8
#define HH 32
#define KVH 8
#define HD 128
#define DD 4096
#define PAST 4094
#define QCOLS 4096
#define KVCOLS 1024
#define NC_QKV 6144
#define DCH 64
#define NDCH 64
#define CHUNK 32
#define NCHUNK 128
#define YBLK 16          // attn blockIdx.y; 8 wave-chunks per block
#define QSCALE 0.08838834764831845f
#define FIN_PER_B 3584

// ---------------- Kernel 1: QKV split-D matvec partials ----------------
// grid (12,64)=768=3/CU. float2 loads (512B/wave/instr; R11 lesson: never
// <8B/lane), unroll 16 = 8KB/wave in flight. NDCH=64 settled (R11/R12).
__global__ __launch_bounds__(256)
void matvec_partial(const float* __restrict__ hin,
                    const float* __restrict__ W0,
                    const float* __restrict__ W1,
                    const float* __restrict__ W2,
                    int c_w1, int c_w2, int NC,
                    float* __restrict__ part)
{
    __shared__ float hl[DCH][BB];
    const int tid = threadIdx.x;
    const int d0 = blockIdx.y * DCH;
    const int cb = blockIdx.x * 512;

    for (int idx = tid; idx < DCH * BB; idx += 256) {
        int dd = idx & (DCH - 1);
        int b = idx >> 6;
        hl[dd][b] = hin[b * DD + d0 + dd];
    }
    __syncthreads();

    const int c = cb + tid * 2;
    const float* W;
    int ldw, cl;
    if (c < c_w1)      { W = W0; ldw = c_w1;        cl = c; }
    else if (c < c_w2) { W = W1; ldw = c_w2 - c_w1; cl = c - c_w1; }
    else               { W = W2; ldw = NC - c_w2;   cl = c - c_w2; }
    const float* wp = W + (size_t)d0 * ldw + cl;

    float2 acc[BB];
    #pragma unroll
    for (int b = 0; b < BB; ++b) { acc[b].x = 0.f; acc[b].y = 0.f; }

    #pragma unroll 16
    for (int dd = 0; dd < DCH; ++dd) {
        float2 w = *(const float2*)wp;
        wp += ldw;
        float hv[8];
        *(float4*)&hv[0] = *(const float4*)&hl[dd][0];
        *(float4*)&hv[4] = *(const float4*)&hl[dd][4];
        #pragma unroll
        for (int b = 0; b < BB; ++b) {
            acc[b].x = fmaf(hv[b], w.x, acc[b].x);
            acc[b].y = fmaf(hv[b], w.y, acc[b].y);
        }
    }

    float* po = part + (size_t)blockIdx.y * (BB * NC) + c;
    #pragma unroll
    for (int b = 0; b < BB; ++b) {
        *(float2*)(po + (size_t)b * NC) = acc[b];
    }
}

// ---------------- Kernel 2: QKV reduce + RoPE (wave-split) ----------------
// 448 blocks; block owns 64 outputs; wave w sums partial slice [16w,16w+16);
// LDS combine; lanes 0..63 apply RoPE and write.
__global__ __launch_bounds__(256)
void qkv_finish(const float* __restrict__ part,
                const float* __restrict__ cosv,
                const float* __restrict__ sinv,
                float* __restrict__ qout,
                float* __restrict__ knew,
                float* __restrict__ vnew)
{
    __shared__ float red[4][64][2];
    const int lane = threadIdx.x & 63;
    const int w = threadIdx.x >> 6;
    const int o = blockIdx.x * 64 + lane;     // < BB*FIN_PER_B
    const int b = o / FIN_PER_B;
    const int r = o - b * FIN_PER_B;

    float s0 = 0.f, s1 = 0.f;
    if (r < 2560) {
        const int hd = r & 63;
        const int head = r >> 6;              // 0..39 (32 q heads + 8 k)
        const int c_lo = head * HD + hd;
        const float* p0 = part + (size_t)b * NC_QKV + c_lo;
        const float* p1 = p0 + 64;
        #pragma unroll 16
        for (int i = w * 16; i < w * 16 + 16; ++i) {
            s0 += p0[(size_t)i * (BB * NC_QKV)];
            s1 += p1[(size_t)i * (BB * NC_QKV)];
        }
    } else {
        const int c = r - 2560 + QCOLS + KVCOLS;
        const float* p = part + (size_t)b * NC_QKV + c;
        #pragma unroll 16
        for (int i = w * 16; i < w * 16 + 16; ++i)
            s0 += p[(size_t)i * (BB * NC_QKV)];
    }
    red[w][lane][0] = s0;
    red[w][lane][1] = s1;
    __syncthreads();

    if (threadIdx.x < 64) {
        const float a0 = red[0][lane][0] + red[1][lane][0]
                       + red[2][lane][0] + red[3][lane][0];
        const float a1 = red[0][lane][1] + red[1][lane][1]
                       + red[2][lane][1] + red[3][lane][1];
        if (r < 2560) {
            const int hd = r & 63;
            const int head = r >> 6;
            const int c_lo = head * HD + hd;
            const float cs_lo = cosv[b * HD + hd];
            const float sn_lo = sinv[b * HD + hd];
            const float cs_hi = cosv[b * HD + hd + 64];
            const float sn_hi = sinv[b * HD + hd + 64];
            const float v_lo = fmaf(a0, cs_lo, -a1 * sn_lo);
            const float v_hi = fmaf(a1, cs_hi,  a0 * sn_hi);
            if (c_lo < QCOLS) {
                qout[b * QCOLS + c_lo]      = v_lo * QSCALE;
                qout[b * QCOLS + c_lo + 64] = v_hi * QSCALE;
            } else {
                knew[b * KVCOLS + (c_lo - QCOLS)]      = v_lo;
                knew[b * KVCOLS + (c_lo - QCOLS) + 64] = v_hi;
            }
        } else {
            const int c = r - 2560;
            vnew[b * KVCOLS + c] = a0;
        }
    }
}

// ---------------- Kernel 3: flash-decode partials ----------------
// grid (64,16) x 512 threads = 1024 blocks = 4/CU = 32 waves/CU (clean
// 32-wave test: VGPR 44-48 <= 64 so 8 waves/SIMD fit natively, LDS
// 16.5KBx4=66KB fits; R7/R8's 32-wave attempts were confounded).
// Wave w owns chunk y*8+w (CHUNK=32 keys), half-wave per key (1 VMEM
// instr/key). 8 waves LDS-combine -> pacc 2.1 MB. NO min-wave
// launch_bounds arg (round-8 spill lesson).
__global__ __launch_bounds__(512)
void attn_partial(const float* __restrict__ past_key,
                  const float* __restrict__ past_value,
                  const float* __restrict__ q,
                  const float* __restrict__ knew,
                  const float* __restrict__ vnew,
                  float* __restrict__ pacc,
                  float* __restrict__ pl)
{
    const int pair = blockIdx.x;       // b*8+kv
    const int wid = threadIdx.x >> 6;  // 0..7
    const int chunk = blockIdx.y * 8 + wid;       // 0..127
    const int b = pair >> 3;
    const int kv = pair & 7;
    const int lane = threadIdx.x & 63;
    const int half = lane >> 5;
    const int lh = lane & 31;

    const float* qb = q + b * QCOLS + (kv * 4) * HD + 4 * lh;
    const float4 qv0 = *(const float4*)(qb);
    const float4 qv1 = *(const float4*)(qb + HD);
    const float4 qv2 = *(const float4*)(qb + 2 * HD);
    const float4 qv3 = *(const float4*)(qb + 3 * HD);

    const float* kb = past_key   + (size_t)pair * PAST * HD;
    const float* vb = past_value + (size_t)pair * PAST * HD;

    float4 acc0 = {0,0,0,0}, acc1 = {0,0,0,0}, acc2 = {0,0,0,0}, acc3 = {0,0,0,0};
    float l0 = 0.f, l1 = 0.f, l2 = 0.f, l3 = 0.f;

    const int jbase = chunk * CHUNK + half;

    if (chunk < NCHUNK - 1) {
        // all 32 keys are valid past keys: pure streaming loop
        const float* kp = kb + (size_t)jbase * HD + 4 * lh;
        const float* vp = vb + (size_t)jbase * HD + 4 * lh;
        #pragma unroll 4
        for (int it = 0; it < 16; ++it) {
            const float4 kk = *(const float4*)kp;  kp += 2 * HD;
            float s0 = kk.x*qv0.x + kk.y*qv0.y + kk.z*qv0.z + kk.w*qv0.w;
            float s1 = kk.x*qv1.x + kk.y*qv1.y + kk.z*qv1.z + kk.w*qv1.w;
            float s2 = kk.x*qv2.x + kk.y*qv2.y + kk.z*qv2.z + kk.w*qv2.w;
            float s3 = kk.x*qv3.x + kk.y*qv3.y + kk.z*qv3.z + kk.w*qv3.w;
            #pragma unroll
            for (int m = 1; m <= 16; m <<= 1) {
                s0 += __shfl_xor(s0, m, 64);
                s1 += __shfl_xor(s1, m, 64);
                s2 += __shfl_xor(s2, m, 64);
                s3 += __shfl_xor(s3, m, 64);
            }
            const float4 vv = *(const float4*)vp;  vp += 2 * HD;
            const float p0 = __expf(s0);
            const float p1 = __expf(s1);
            const float p2 = __expf(s2);
            const float p3 = __expf(s3);
            l0 += p0; l1 += p1; l2 += p2; l3 += p3;
            acc0.x = fmaf(p0, vv.x, acc0.x); acc0.y = fmaf(p0, vv.y, acc0.y);
            acc0.z = fmaf(p0, vv.z, acc0.z); acc0.w = fmaf(p0, vv.w, acc0.w);
            acc1.x = fmaf(p1, vv.x, acc1.x); acc1.y = fmaf(p1, vv.y, acc1.y);
            acc1.z = fmaf(p1, vv.z, acc1.z); acc1.w = fmaf(p1, vv.w, acc1.w);
            acc2.x = fmaf(p2, vv.x, acc2.x); acc2.y = fmaf(p2, vv.y, acc2.y);
            acc2.z = fmaf(p2, vv.z, acc2.z); acc2.w = fmaf(p2, vv.w, acc2.w);
            acc3.x = fmaf(p3, vv.x, acc3.x); acc3.y = fmaf(p3, vv.y, acc3.y);
            acc3.z = fmaf(p3, vv.z, acc3.z); acc3.w = fmaf(p3, vv.w, acc3.w);
        }
    } else {
        // boundary chunk: new rope'd key at j==PAST, masked-out j==PAST+1
        const float* kn = knew + pair * HD;
        const float* vn = vnew + pair * HD;
        #pragma unroll 2
        for (int it = 0; it < 16; ++it) {
            const int j = jbase + it * 2;
            const bool valid = (j <= PAST);
            const float* kp;
            const float* vp;
            if (j < PAST) { kp = kb + (size_t)j * HD; vp = vb + (size_t)j * HD; }
            else          { kp = kn;                   vp = vn; }

            const float4 kk = *(const float4*)(kp + 4 * lh);
            float s0 = kk.x*qv0.x + kk.y*qv0.y + kk.z*qv0.z + kk.w*qv0.w;
            float s1 = kk.x*qv1.x + kk.y*qv1.y + kk.z*qv1.z + kk.w*qv1.w;
            float s2 = kk.x*qv2.x + kk.y*qv2.y + kk.z*qv2.z + kk.w*qv2.w;
            float s3 = kk.x*qv3.x + kk.y*qv3.y + kk.z*qv3.z + kk.w*qv3.w;
            #pragma unroll
            for (int m = 1; m <= 16; m <<= 1) {
                s0 += __shfl_xor(s0, m, 64);
                s1 += __shfl_xor(s1, m, 64);
                s2 += __shfl_xor(s2, m, 64);
                s3 += __shfl_xor(s3, m, 64);
            }
            const float4 vv = *(const float4*)(vp + 4 * lh);
            const float p0 = valid ? __expf(s0) : 0.f;
            const float p1 = valid ? __expf(s1) : 0.f;
            const float p2 = valid ? __expf(s2) : 0.f;
            const float p3 = valid ? __expf(s3) : 0.f;
            l0 += p0; l1 += p1; l2 += p2; l3 += p3;
            acc0.x = fmaf(p0, vv.x, acc0.x); acc0.y = fmaf(p0, vv.y, acc0.y);
            acc0.z = fmaf(p0, vv.z, acc0.z); acc0.w = fmaf(p0, vv.w, acc0.w);
            acc1.x = fmaf(p1, vv.x, acc1.x); acc1.y = fmaf(p1, vv.y, acc1.y);
            acc1.z = fmaf(p1, vv.z, acc1.z); acc1.w = fmaf(p1, vv.w, acc1.w);
            acc2.x = fmaf(p2, vv.x, acc2.x); acc2.y = fmaf(p2, vv.y, acc2.y);
            acc2.z = fmaf(p2, vv.z, acc2.z); acc2.w = fmaf(p2, vv.w, acc2.w);
            acc3.x = fmaf(p3, vv.x, acc3.x); acc3.y = fmaf(p3, vv.y, acc3.y);
            acc3.z = fmaf(p3, vv.z, acc3.z); acc3.w = fmaf(p3, vv.w, acc3.w);
        }
    }

    // combine the two halves (even/odd keys) within the wave
    l0 += __shfl_xor(l0, 32, 64);
    l1 += __shfl_xor(l1, 32, 64);
    l2 += __shfl_xor(l2, 32, 64);
    l3 += __shfl_xor(l3, 32, 64);
    acc0.x += __shfl_xor(acc0.x, 32, 64); acc0.y += __shfl_xor(acc0.y, 32, 64);
    acc0.z += __shfl_xor(acc0.z, 32, 64); acc0.w += __shfl_xor(acc0.w, 32, 64);
    acc1.x += __shfl_xor(acc1.x, 32, 64); acc1.y += __shfl_xor(acc1.y, 32, 64);
    acc1.z += __shfl_xor(acc1.z, 32, 64); acc1.w += __shfl_xor(acc1.w, 32, 64);
    acc2.x += __shfl_xor(acc2.x, 32, 64); acc2.y += __shfl_xor(acc2.y, 32, 64);
    acc2.z += __shfl_xor(acc2.z, 32, 64); acc2.w += __shfl_xor(acc2.w, 32, 64);
    acc3.x += __shfl_xor(acc3.x, 32, 64); acc3.y += __shfl_xor(acc3.y, 32, 64);
    acc3.z += __shfl_xor(acc3.z, 32, 64); acc3.w += __shfl_xor(acc3.w, 32, 64);

    // block-level combine of the 8 wave-chunks via LDS (~16.5 KB)
    __shared__ float lacc[8][4][HD];
    __shared__ float ll[8][4];
    if (half == 0) {
        *(float4*)&lacc[wid][0][4 * lh] = acc0;
        *(float4*)&lacc[wid][1][4 * lh] = acc1;
        *(float4*)&lacc[wid][2][4 * lh] = acc2;
        *(float4*)&lacc[wid][3][4 * lh] = acc3;
        if (lh == 0) {
            ll[wid][0] = l0; ll[wid][1] = l1; ll[wid][2] = l2; ll[wid][3] = l3;
        }
    }
    __syncthreads();
    if (threadIdx.x < 256) {
        const int head = threadIdx.x >> 6;      // wave -> head
        const int d2 = (threadIdx.x & 63) * 2;
        float ax = 0.f, ay = 0.f;
        #pragma unroll
        for (int w = 0; w < 8; ++w) {
            ax += lacc[w][head][d2];
            ay += lacc[w][head][d2 + 1];
        }
        float* po = pacc + (((size_t)pair * YBLK + blockIdx.y) * 4 + head) * HD + d2;
        float2 r; r.x = ax; r.y = ay;
        *(float2*)po = r;
        if ((threadIdx.x & 63) == 0) {
            float L = 0.f;
            #pragma unroll
            for (int w = 0; w < 8; ++w) L += ll[w][head];
            pl[((size_t)pair * YBLK + blockIdx.y) * 4 + head] = L;
        }
    }
}

// ------- Kernel 4: Wo matvec with FUSED attn-combine staging ----------
// grid (8,64)=512=2/CU. Staging computes the attn output on the fly from
// pacc/pl (depth-16 sums; pacc 2.1 MB, L2/L3-resident). Deletes the
// attn_combine kernel + its launch gap + the attn_out round-trip.
__global__ __launch_bounds__(256)
void wo_matvec_fused(const float* __restrict__ pacc,
                     const float* __restrict__ pl,
                     const float* __restrict__ W,
                     float* __restrict__ part)
{
    __shared__ float hl[DCH][BB];
    const int tid = threadIdx.x;
    const int d0 = blockIdx.y * DCH;
    const int cb = blockIdx.x * 512;

    for (int idx = tid; idx < DCH * BB; idx += 256) {
        const int dd = idx & (DCH - 1);
        const int b = idx >> 6;
        const int c = d0 + dd;            // attn column = h*HD + d
        const int h = c >> 7;
        const int d = c & 127;
        const int pair = b * 8 + (h >> 2);
        const int qi = h & 3;
        const float* pa  = pacc + ((size_t)pair * YBLK * 4 + qi) * HD + d;
        const float* pls = pl + (size_t)pair * YBLK * 4 + qi;
        float a = 0.f, L = 0.f;
        #pragma unroll
        for (int y = 0; y < YBLK; ++y) {
            a += pa[(size_t)y * 4 * HD];
            L += pls[y * 4];
        }
        hl[dd][b] = a / L;
    }
    __syncthreads();

    const int c = cb + tid * 2;
    const float* wp = W + (size_t)d0 * QCOLS + c;

    float2 acc[BB];
    #pragma unroll
    for (int b = 0; b < BB; ++b) { acc[b].x = 0.f; acc[b].y = 0.f; }

    #pragma unroll 16
    for (int dd = 0; dd < DCH; ++dd) {
        float2 w = *(const float2*)wp;
        wp += QCOLS;
        float hv[8];
        *(float4*)&hv[0] = *(const float4*)&hl[dd][0];
        *(float4*)&hv[4] = *(const float4*)&hl[dd][4];
        #pragma unroll
        for (int b = 0; b < BB; ++b) {
            acc[b].x = fmaf(hv[b], w.x, acc[b].x);
            acc[b].y = fmaf(hv[b], w.y, acc[b].y);
        }
    }

    float* po = part + (size_t)blockIdx.y * (BB * QCOLS) + c;
    #pragma unroll
    for (int b = 0; b < BB; ++b) {
        *(float2*)(po + (size_t)b * QCOLS) = acc[b];
    }
}

// ---------------- Kernel 5: Wo reduce (wave-split, depth 64) ----------
// 512 blocks; block owns 64 outputs; wave w sums slice [16w,16w+16).
__global__ __launch_bounds__(256)
void wo_finish(const float* __restrict__ part, float* __restrict__ out)
{
    __shared__ float red[4][64];
    const int lane = threadIdx.x & 63;
    const int w = threadIdx.x >> 6;
    const int o = blockIdx.x * 64 + lane;   // < 8*4096
    const float* p = part + o;
    float s = 0.f;
    #pragma unroll 16
    for (int i = w * 16; i < w * 16 + 16; ++i)
        s += p[(size_t)i * (BB * QCOLS)];
    red[w][lane] = s;
    __syncthreads();
    if (threadIdx.x < 64) {
        out[o] = red[0][lane] + red[1][lane] + red[2][lane] + red[3][lane];
    }
}

extern "C" void kernel_launch(void* const* d_in, const int* in_sizes, int n_in,
                              void* d_out, int out_size, void* d_ws, size_t ws_size,
                              hipStream_t stream)
{
    (void)in_sizes; (void)n_in; (void)out_size; (void)ws_size;
    const float* hidden     = (const float*)d_in[0];
    const float* cosv       = (const float*)d_in[2];
    const float* sinv       = (const float*)d_in[3];
    const float* past_key   = (const float*)d_in[4];
    const float* past_value = (const float*)d_in[5];
    // d_in[1] mask, d_in[6] k_cache, d_in[7] v_cache: provably unused (mask
    // zeroes position 4095 exactly; positions < 4094 come from past_key/value)
    const float* Wq = (const float*)d_in[8];
    const float* Wk = (const float*)d_in[9];
    const float* Wv = (const float*)d_in[10];
    const float* Wo = (const float*)d_in[11];
    float* out = (float*)d_out;
    float* ws  = (float*)d_ws;

    float* qkv_part = ws;                                      // 64*8*6144
    float* qrope    = qkv_part + (size_t)NDCH * BB * NC_QKV;   // 32768
    float* knew     = qrope + BB * QCOLS;                      // 8192
    float* vnew     = knew + BB * KVCOLS;                      // 8192
    float* pacc     = vnew + BB * KVCOLS;                      // 64*16*4*128
    float* pl       = pacc + (size_t)64 * YBLK * 4 * HD;       // 64*16*4
    float* wo_part  = qkv_part;                                // reuse

    matvec_partial<<<dim3(12, NDCH), 256, 0, stream>>>(
        hidden, Wq, Wk, Wv, 4096, 5120, NC_QKV, qkv_part);
    qkv_finish<<<(BB * FIN_PER_B) / 64, 256, 0, stream>>>(
        qkv_part, cosv, sinv, qrope, knew, vnew);
    attn_partial<<<dim3(64, YBLK), 512, 0, stream>>>(
        past_key, past_value, qrope, knew, vnew, pacc, pl);
    wo_matvec_fused<<<dim3(8, NDCH), 256, 0, stream>>>(
        pacc, pl, Wo, wo_part);
    wo_finish<<<(BB * QCOLS) / 64, 256, 0, stream>>>(wo_part, out);
}

// Round 15
// 103.555 us; speedup vs baseline: 1.0316x; 1.0316x over previous
//
#include <hip/hip_runtime.h>

#define BB 8
#define HH 32
#define KVH 8
#define HD 128
#define DD 4096
#define PAST 4094
#define QCOLS 4096
#define KVCOLS 1024
#define NC_QKV 6144
#define DCH 64
#define NDCH 64
#define CHUNK 64
#define NCHUNK 64
#define YBLK 8           // attn blockIdx.y; 8 wave-chunks per block
#define QSCALE 0.08838834764831845f
#define FIN_PER_B 3584

// ---------------- Kernel 1: QKV split-D matvec partials ----------------
// grid (12,64)=768=3/CU. float2 loads (512B/wave/instr; R11 lesson: never
// <8B/lane), unroll 16 = 8KB/wave in flight. NDCH=64 settled (R11/R12:
// depth-halving dies on occupancy/stream efficiency).
__global__ __launch_bounds__(256)
void matvec_partial(const float* __restrict__ hin,
                    const float* __restrict__ W0,
                    const float* __restrict__ W1,
                    const float* __restrict__ W2,
                    int c_w1, int c_w2, int NC,
                    float* __restrict__ part)
{
    __shared__ float hl[DCH][BB];
    const int tid = threadIdx.x;
    const int d0 = blockIdx.y * DCH;
    const int cb = blockIdx.x * 512;

    for (int idx = tid; idx < DCH * BB; idx += 256) {
        int dd = idx & (DCH - 1);
        int b = idx >> 6;
        hl[dd][b] = hin[b * DD + d0 + dd];
    }
    __syncthreads();

    const int c = cb + tid * 2;
    const float* W;
    int ldw, cl;
    if (c < c_w1)      { W = W0; ldw = c_w1;        cl = c; }
    else if (c < c_w2) { W = W1; ldw = c_w2 - c_w1; cl = c - c_w1; }
    else               { W = W2; ldw = NC - c_w2;   cl = c - c_w2; }
    const float* wp = W + (size_t)d0 * ldw + cl;

    float2 acc[BB];
    #pragma unroll
    for (int b = 0; b < BB; ++b) { acc[b].x = 0.f; acc[b].y = 0.f; }

    #pragma unroll 16
    for (int dd = 0; dd < DCH; ++dd) {
        float2 w = *(const float2*)wp;
        wp += ldw;
        float hv[8];
        *(float4*)&hv[0] = *(const float4*)&hl[dd][0];
        *(float4*)&hv[4] = *(const float4*)&hl[dd][4];
        #pragma unroll
        for (int b = 0; b < BB; ++b) {
            acc[b].x = fmaf(hv[b], w.x, acc[b].x);
            acc[b].y = fmaf(hv[b], w.y, acc[b].y);
        }
    }

    float* po = part + (size_t)blockIdx.y * (BB * NC) + c;
    #pragma unroll
    for (int b = 0; b < BB; ++b) {
        *(float2*)(po + (size_t)b * NC) = acc[b];
    }
}

// ---------------- Kernel 2: QKV reduce + RoPE (wave-split) ----------------
// 448 blocks; block owns 64 outputs; wave w sums partial slice [16w,16w+16);
// LDS combine; lanes 0..63 apply RoPE and write.
__global__ __launch_bounds__(256)
void qkv_finish(const float* __restrict__ part,
                const float* __restrict__ cosv,
                const float* __restrict__ sinv,
                float* __restrict__ qout,
                float* __restrict__ knew,
                float* __restrict__ vnew)
{
    __shared__ float red[4][64][2];
    const int lane = threadIdx.x & 63;
    const int w = threadIdx.x >> 6;
    const int o = blockIdx.x * 64 + lane;     // < BB*FIN_PER_B
    const int b = o / FIN_PER_B;
    const int r = o - b * FIN_PER_B;

    float s0 = 0.f, s1 = 0.f;
    if (r < 2560) {
        const int hd = r & 63;
        const int head = r >> 6;              // 0..39 (32 q heads + 8 k)
        const int c_lo = head * HD + hd;
        const float* p0 = part + (size_t)b * NC_QKV + c_lo;
        const float* p1 = p0 + 64;
        #pragma unroll 16
        for (int i = w * 16; i < w * 16 + 16; ++i) {
            s0 += p0[(size_t)i * (BB * NC_QKV)];
            s1 += p1[(size_t)i * (BB * NC_QKV)];
        }
    } else {
        const int c = r - 2560 + QCOLS + KVCOLS;
        const float* p = part + (size_t)b * NC_QKV + c;
        #pragma unroll 16
        for (int i = w * 16; i < w * 16 + 16; ++i)
            s0 += p[(size_t)i * (BB * NC_QKV)];
    }
    red[w][lane][0] = s0;
    red[w][lane][1] = s1;
    __syncthreads();

    if (threadIdx.x < 64) {
        const float a0 = red[0][lane][0] + red[1][lane][0]
                       + red[2][lane][0] + red[3][lane][0];
        const float a1 = red[0][lane][1] + red[1][lane][1]
                       + red[2][lane][1] + red[3][lane][1];
        if (r < 2560) {
            const int hd = r & 63;
            const int head = r >> 6;
            const int c_lo = head * HD + hd;
            const float cs_lo = cosv[b * HD + hd];
            const float sn_lo = sinv[b * HD + hd];
            const float cs_hi = cosv[b * HD + hd + 64];
            const float sn_hi = sinv[b * HD + hd + 64];
            const float v_lo = fmaf(a0, cs_lo, -a1 * sn_lo);
            const float v_hi = fmaf(a1, cs_hi,  a0 * sn_hi);
            if (c_lo < QCOLS) {
                qout[b * QCOLS + c_lo]      = v_lo * QSCALE;
                qout[b * QCOLS + c_lo + 64] = v_hi * QSCALE;
            } else {
                knew[b * KVCOLS + (c_lo - QCOLS)]      = v_lo;
                knew[b * KVCOLS + (c_lo - QCOLS) + 64] = v_hi;
            }
        } else {
            const int c = r - 2560;
            vnew[b * KVCOLS + c] = a0;
        }
    }
}

// ---------------- Kernel 3: flash-decode partials (R10/R13 config) -------
// grid (64 pairs, 8) x 512 threads = 512 blocks = 2/CU = 16 waves/CU
// (settled: 8 waves starves latency-hiding [R6], 32 waves adds prologue
// cost for zero BW gain [R14]). Wave w owns chunk y*8+w (CHUNK=64 keys),
// half-wave per key (1 VMEM instr/key), 32 lanes x float4 own the dims.
// 8 waves LDS-combine -> pacc 1.05 MB. NO min-wave launch_bounds arg
// (round-8 spill lesson).
__global__ __launch_bounds__(512)
void attn_partial(const float* __restrict__ past_key,
                  const float* __restrict__ past_value,
                  const float* __restrict__ q,
                  const float* __restrict__ knew,
                  const float* __restrict__ vnew,
                  float* __restrict__ pacc,
                  float* __restrict__ pl)
{
    const int pair = blockIdx.x;       // b*8+kv
    const int wid = threadIdx.x >> 6;  // 0..7
    const int chunk = blockIdx.y * 8 + wid;       // 0..63
    const int b = pair >> 3;
    const int kv = pair & 7;
    const int lane = threadIdx.x & 63;
    const int half = lane >> 5;
    const int lh = lane & 31;

    const float* qb = q + b * QCOLS + (kv * 4) * HD + 4 * lh;
    const float4 qv0 = *(const float4*)(qb);
    const float4 qv1 = *(const float4*)(qb + HD);
    const float4 qv2 = *(const float4*)(qb + 2 * HD);
    const float4 qv3 = *(const float4*)(qb + 3 * HD);

    const float* kb = past_key   + (size_t)pair * PAST * HD;
    const float* vb = past_value + (size_t)pair * PAST * HD;

    float4 acc0 = {0,0,0,0}, acc1 = {0,0,0,0}, acc2 = {0,0,0,0}, acc3 = {0,0,0,0};
    float l0 = 0.f, l1 = 0.f, l2 = 0.f, l3 = 0.f;

    const int jbase = chunk * CHUNK + half;

    if (chunk < NCHUNK - 1) {
        // all 64 keys are valid past keys: pure streaming loop
        const float* kp = kb + (size_t)jbase * HD + 4 * lh;
        const float* vp = vb + (size_t)jbase * HD + 4 * lh;
        #pragma unroll 4
        for (int it = 0; it < 32; ++it) {
            const float4 kk = *(const float4*)kp;  kp += 2 * HD;
            float s0 = kk.x*qv0.x + kk.y*qv0.y + kk.z*qv0.z + kk.w*qv0.w;
            float s1 = kk.x*qv1.x + kk.y*qv1.y + kk.z*qv1.z + kk.w*qv1.w;
            float s2 = kk.x*qv2.x + kk.y*qv2.y + kk.z*qv2.z + kk.w*qv2.w;
            float s3 = kk.x*qv3.x + kk.y*qv3.y + kk.z*qv3.z + kk.w*qv3.w;
            #pragma unroll
            for (int m = 1; m <= 16; m <<= 1) {
                s0 += __shfl_xor(s0, m, 64);
                s1 += __shfl_xor(s1, m, 64);
                s2 += __shfl_xor(s2, m, 64);
                s3 += __shfl_xor(s3, m, 64);
            }
            const float4 vv = *(const float4*)vp;  vp += 2 * HD;
            const float p0 = __expf(s0);
            const float p1 = __expf(s1);
            const float p2 = __expf(s2);
            const float p3 = __expf(s3);
            l0 += p0; l1 += p1; l2 += p2; l3 += p3;
            acc0.x = fmaf(p0, vv.x, acc0.x); acc0.y = fmaf(p0, vv.y, acc0.y);
            acc0.z = fmaf(p0, vv.z, acc0.z); acc0.w = fmaf(p0, vv.w, acc0.w);
            acc1.x = fmaf(p1, vv.x, acc1.x); acc1.y = fmaf(p1, vv.y, acc1.y);
            acc1.z = fmaf(p1, vv.z, acc1.z); acc1.w = fmaf(p1, vv.w, acc1.w);
            acc2.x = fmaf(p2, vv.x, acc2.x); acc2.y = fmaf(p2, vv.y, acc2.y);
            acc2.z = fmaf(p2, vv.z, acc2.z); acc2.w = fmaf(p2, vv.w, acc2.w);
            acc3.x = fmaf(p3, vv.x, acc3.x); acc3.y = fmaf(p3, vv.y, acc3.y);
            acc3.z = fmaf(p3, vv.z, acc3.z); acc3.w = fmaf(p3, vv.w, acc3.w);
        }
    } else {
        // boundary chunk: new rope'd key at j==PAST, masked-out j==PAST+1
        const float* kn = knew + pair * HD;
        const float* vn = vnew + pair * HD;
        #pragma unroll 2
        for (int it = 0; it < 32; ++it) {
            const int j = jbase + it * 2;
            const bool valid = (j <= PAST);
            const float* kp;
            const float* vp;
            if (j < PAST) { kp = kb + (size_t)j * HD; vp = vb + (size_t)j * HD; }
            else          { kp = kn;                   vp = vn; }

            const float4 kk = *(const float4*)(kp + 4 * lh);
            float s0 = kk.x*qv0.x + kk.y*qv0.y + kk.z*qv0.z + kk.w*qv0.w;
            float s1 = kk.x*qv1.x + kk.y*qv1.y + kk.z*qv1.z + kk.w*qv1.w;
            float s2 = kk.x*qv2.x + kk.y*qv2.y + kk.z*qv2.z + kk.w*qv2.w;
            float s3 = kk.x*qv3.x + kk.y*qv3.y + kk.z*qv3.z + kk.w*qv3.w;
            #pragma unroll
            for (int m = 1; m <= 16; m <<= 1) {
                s0 += __shfl_xor(s0, m, 64);
                s1 += __shfl_xor(s1, m, 64);
                s2 += __shfl_xor(s2, m, 64);
                s3 += __shfl_xor(s3, m, 64);
            }
            const float4 vv = *(const float4*)(vp + 4 * lh);
            const float p0 = valid ? __expf(s0) : 0.f;
            const float p1 = valid ? __expf(s1) : 0.f;
            const float p2 = valid ? __expf(s2) : 0.f;
            const float p3 = valid ? __expf(s3) : 0.f;
            l0 += p0; l1 += p1; l2 += p2; l3 += p3;
            acc0.x = fmaf(p0, vv.x, acc0.x); acc0.y = fmaf(p0, vv.y, acc0.y);
            acc0.z = fmaf(p0, vv.z, acc0.z); acc0.w = fmaf(p0, vv.w, acc0.w);
            acc1.x = fmaf(p1, vv.x, acc1.x); acc1.y = fmaf(p1, vv.y, acc1.y);
            acc1.z = fmaf(p1, vv.z, acc1.z); acc1.w = fmaf(p1, vv.w, acc1.w);
            acc2.x = fmaf(p2, vv.x, acc2.x); acc2.y = fmaf(p2, vv.y, acc2.y);
            acc2.z = fmaf(p2, vv.z, acc2.z); acc2.w = fmaf(p2, vv.w, acc2.w);
            acc3.x = fmaf(p3, vv.x, acc3.x); acc3.y = fmaf(p3, vv.y, acc3.y);
            acc3.z = fmaf(p3, vv.z, acc3.z); acc3.w = fmaf(p3, vv.w, acc3.w);
        }
    }

    // combine the two halves (even/odd keys) within the wave
    l0 += __shfl_xor(l0, 32, 64);
    l1 += __shfl_xor(l1, 32, 64);
    l2 += __shfl_xor(l2, 32, 64);
    l3 += __shfl_xor(l3, 32, 64);
    acc0.x += __shfl_xor(acc0.x, 32, 64); acc0.y += __shfl_xor(acc0.y, 32, 64);
    acc0.z += __shfl_xor(acc0.z, 32, 64); acc0.w += __shfl_xor(acc0.w, 32, 64);
    acc1.x += __shfl_xor(acc1.x, 32, 64); acc1.y += __shfl_xor(acc1.y, 32, 64);
    acc1.z += __shfl_xor(acc1.z, 32, 64); acc1.w += __shfl_xor(acc1.w, 32, 64);
    acc2.x += __shfl_xor(acc2.x, 32, 64); acc2.y += __shfl_xor(acc2.y, 32, 64);
    acc2.z += __shfl_xor(acc2.z, 32, 64); acc2.w += __shfl_xor(acc2.w, 32, 64);
    acc3.x += __shfl_xor(acc3.x, 32, 64); acc3.y += __shfl_xor(acc3.y, 32, 64);
    acc3.z += __shfl_xor(acc3.z, 32, 64); acc3.w += __shfl_xor(acc3.w, 32, 64);

    // block-level combine of the 8 wave-chunks via LDS (~16.5 KB)
    __shared__ float lacc[8][4][HD];
    __shared__ float ll[8][4];
    if (half == 0) {
        *(float4*)&lacc[wid][0][4 * lh] = acc0;
        *(float4*)&lacc[wid][1][4 * lh] = acc1;
        *(float4*)&lacc[wid][2][4 * lh] = acc2;
        *(float4*)&lacc[wid][3][4 * lh] = acc3;
        if (lh == 0) {
            ll[wid][0] = l0; ll[wid][1] = l1; ll[wid][2] = l2; ll[wid][3] = l3;
        }
    }
    __syncthreads();
    if (threadIdx.x < 256) {
        const int head = threadIdx.x >> 6;      // wave -> head
        const int d2 = (threadIdx.x & 63) * 2;
        float ax = 0.f, ay = 0.f;
        #pragma unroll
        for (int w = 0; w < 8; ++w) {
            ax += lacc[w][head][d2];
            ay += lacc[w][head][d2 + 1];
        }
        float* po = pacc + (((size_t)pair * YBLK + blockIdx.y) * 4 + head) * HD + d2;
        float2 r; r.x = ax; r.y = ay;
        *(float2*)po = r;
        if ((threadIdx.x & 63) == 0) {
            float L = 0.f;
            #pragma unroll
            for (int w = 0; w < 8; ++w) L += ll[w][head];
            pl[((size_t)pair * YBLK + blockIdx.y) * 4 + head] = L;
        }
    }
}

// ------- Kernel 4: Wo matvec with FUSED attn-combine staging ----------
// grid (8,64)=512=2/CU. Staging computes the attn output on the fly from
// pacc/pl (depth-8 sums; pacc 1.05 MB, L2-resident). Deletes the
// attn_combine kernel + its launch gap + the attn_out round-trip.
__global__ __launch_bounds__(256)
void wo_matvec_fused(const float* __restrict__ pacc,
                     const float* __restrict__ pl,
                     const float* __restrict__ W,
                     float* __restrict__ part)
{
    __shared__ float hl[DCH][BB];
    const int tid = threadIdx.x;
    const int d0 = blockIdx.y * DCH;
    const int cb = blockIdx.x * 512;

    for (int idx = tid; idx < DCH * BB; idx += 256) {
        const int dd = idx & (DCH - 1);
        const int b = idx >> 6;
        const int c = d0 + dd;            // attn column = h*HD + d
        const int h = c >> 7;
        const int d = c & 127;
        const int pair = b * 8 + (h >> 2);
        const int qi = h & 3;
        const float* pa  = pacc + ((size_t)pair * YBLK * 4 + qi) * HD + d;
        const float* pls = pl + (size_t)pair * YBLK * 4 + qi;
        float a = 0.f, L = 0.f;
        #pragma unroll
        for (int y = 0; y < YBLK; ++y) {
            a += pa[(size_t)y * 4 * HD];
            L += pls[y * 4];
        }
        hl[dd][b] = a / L;
    }
    __syncthreads();

    const int c = cb + tid * 2;
    const float* wp = W + (size_t)d0 * QCOLS + c;

    float2 acc[BB];
    #pragma unroll
    for (int b = 0; b < BB; ++b) { acc[b].x = 0.f; acc[b].y = 0.f; }

    #pragma unroll 16
    for (int dd = 0; dd < DCH; ++dd) {
        float2 w = *(const float2*)wp;
        wp += QCOLS;
        float hv[8];
        *(float4*)&hv[0] = *(const float4*)&hl[dd][0];
        *(float4*)&hv[4] = *(const float4*)&hl[dd][4];
        #pragma unroll
        for (int b = 0; b < BB; ++b) {
            acc[b].x = fmaf(hv[b], w.x, acc[b].x);
            acc[b].y = fmaf(hv[b], w.y, acc[b].y);
        }
    }

    float* po = part + (size_t)blockIdx.y * (BB * QCOLS) + c;
    #pragma unroll
    for (int b = 0; b < BB; ++b) {
        *(float2*)(po + (size_t)b * QCOLS) = acc[b];
    }
}

// ---------------- Kernel 5: Wo reduce (wave-split, depth 64) ----------
// 512 blocks; block owns 64 outputs; wave w sums slice [16w,16w+16).
__global__ __launch_bounds__(256)
void wo_finish(const float* __restrict__ part, float* __restrict__ out)
{
    __shared__ float red[4][64];
    const int lane = threadIdx.x & 63;
    const int w = threadIdx.x >> 6;
    const int o = blockIdx.x * 64 + lane;   // < 8*4096
    const float* p = part + o;
    float s = 0.f;
    #pragma unroll 16
    for (int i = w * 16; i < w * 16 + 16; ++i)
        s += p[(size_t)i * (BB * QCOLS)];
    red[w][lane] = s;
    __syncthreads();
    if (threadIdx.x < 64) {
        out[o] = red[0][lane] + red[1][lane] + red[2][lane] + red[3][lane];
    }
}

extern "C" void kernel_launch(void* const* d_in, const int* in_sizes, int n_in,
                              void* d_out, int out_size, void* d_ws, size_t ws_size,
                              hipStream_t stream)
{
    (void)in_sizes; (void)n_in; (void)out_size; (void)ws_size;
    const float* hidden     = (const float*)d_in[0];
    const float* cosv       = (const float*)d_in[2];
    const float* sinv       = (const float*)d_in[3];
    const float* past_key   = (const float*)d_in[4];
    const float* past_value = (const float*)d_in[5];
    // d_in[1] mask, d_in[6] k_cache, d_in[7] v_cache: provably unused (mask
    // zeroes position 4095 exactly; positions < 4094 come from past_key/value)
    const float* Wq = (const float*)d_in[8];
    const float* Wk = (const float*)d_in[9];
    const float* Wv = (const float*)d_in[10];
    const float* Wo = (const float*)d_in[11];
    float* out = (float*)d_out;
    float* ws  = (float*)d_ws;

    float* qkv_part = ws;                                      // 64*8*6144
    float* qrope    = qkv_part + (size_t)NDCH * BB * NC_QKV;   // 32768
    float* knew     = qrope + BB * QCOLS;                      // 8192
    float* vnew     = knew + BB * KVCOLS;                      // 8192
    float* pacc     = vnew + BB * KVCOLS;                      // 64*8*4*128
    float* pl       = pacc + (size_t)64 * YBLK * 4 * HD;       // 64*8*4
    float* wo_part  = qkv_part;                                // reuse

    matvec_partial<<<dim3(12, NDCH), 256, 0, stream>>>(
        hidden, Wq, Wk, Wv, 4096, 5120, NC_QKV, qkv_part);
    qkv_finish<<<(BB * FIN_PER_B) / 64, 256, 0, stream>>>(
        qkv_part, cosv, sinv, qrope, knew, vnew);
    attn_partial<<<dim3(64, YBLK), 512, 0, stream>>>(
        past_key, past_value, qrope, knew, vnew, pacc, pl);
    wo_matvec_fused<<<dim3(8, NDCH), 256, 0, stream>>>(
        pacc, pl, Wo, wo_part);
    wo_finish<<<(BB * QCOLS) / 64, 256, 0, stream>>>(wo_part, out);
}